// Round 4
// baseline (179.471 us; speedup 1.0000x reference)
//
#include <hip/hip_runtime.h>
#include <hip/hip_bf16.h>

typedef __attribute__((ext_vector_type(8))) short bf16x8;
typedef __attribute__((ext_vector_type(4))) float f32x4;
typedef __attribute__((ext_vector_type(16))) float f32x16;
typedef __attribute__((ext_vector_type(4))) unsigned int u32x4;

#define MFMA16(a, b, c) __builtin_amdgcn_mfma_f32_16x16x32_bf16((a), (b), (c), 0, 0, 0)
#define MFMA32(a, b, c) __builtin_amdgcn_mfma_f32_32x32x16_bf16((a), (b), (c), 0, 0, 0)

static constexpr int BATCH = 4, S = 2048, DMODEL = 512, H = 8, HD = 64;
static constexpr int M = BATCH * S;  // 8192

// round-to-nearest-even f32 -> bf16 (bit trick; inputs finite)
__device__ __forceinline__ short f2b(float f) {
  unsigned int u = __builtin_bit_cast(unsigned int, f);
  unsigned int r = (u + 0x7fffu + ((u >> 16) & 1u)) >> 16;
  return (short)r;
}

__device__ __forceinline__ bf16x8 cvt8(const float4& a, const float4& b) {
  bf16x8 r;
  r[0] = f2b(a.x); r[1] = f2b(a.y); r[2] = f2b(a.z); r[3] = f2b(a.w);
  r[4] = f2b(b.x); r[5] = f2b(b.y); r[6] = f2b(b.z); r[7] = f2b(b.w);
  return r;
}

// ---------------- weight fp32 -> bf16 ----------------
__global__ __launch_bounds__(256) void convert_w(
    const float* __restrict__ Wq, const float* __restrict__ Wk,
    const float* __restrict__ Wv, const float* __restrict__ Wo,
    short* __restrict__ Wb) {
  const float* src = (blockIdx.y == 0) ? Wq : (blockIdx.y == 1) ? Wk
                   : (blockIdx.y == 2) ? Wv : Wo;
  short* dst = Wb + blockIdx.y * (DMODEL * DMODEL);
  int i = (blockIdx.x * 256 + threadIdx.x) * 8;
  float4 a = *(const float4*)&src[i];
  float4 b = *(const float4*)&src[i + 4];
  *(bf16x8*)&dst[i] = cvt8(a, b);
}

// ---------------- fused Q/K/V projection: C = A @ W^T + b ----------------
// Q,K scatter to [B,H,S,HD]; V scatters TRANSPOSED to [B,H,HD,S] so the
// attention PV A-operand reads straight from global (no LDS transpose).
__global__ __launch_bounds__(256) void proj_gemm(
    const float* __restrict__ Aq, const float* __restrict__ Ak, const float* __restrict__ Av,
    const short* __restrict__ Wb,
    const float* __restrict__ bq, const float* __restrict__ bk, const float* __restrict__ bv,
    short* __restrict__ Qp, short* __restrict__ Kp, short* __restrict__ Vp) {
  const int which = blockIdx.y;
  const float* A    = (which == 0) ? Aq : (which == 1) ? Ak : Av;
  const short* W    = Wb + which * (DMODEL * DMODEL);
  const float* bias = (which == 0) ? bq : (which == 1) ? bk : bv;
  short* dst        = (which == 0) ? Qp : (which == 1) ? Kp : Vp;

  const int tm = blockIdx.x & 63;
  const int tn = blockIdx.x >> 6;
  const int m0 = tm * 128, n0 = tn * 128;
  const int t = threadIdx.x;
  const int lane = t & 63, w = t >> 6;
  const int g = lane >> 4, c = lane & 15;
  const int wr = w >> 1, wc = w & 1;

  __shared__ __align__(16) short As[128 * 32];
  __shared__ __align__(16) short Bs[128 * 32];

  f32x4 acc[4][4];
  const f32x4 fz = {0.f, 0.f, 0.f, 0.f};
#pragma unroll
  for (int i = 0; i < 4; ++i)
#pragma unroll
    for (int j = 0; j < 4; ++j) acc[i][j] = fz;

  const int r0 = t >> 2, c0 = (t & 3) * 8;
  const int r1 = (t + 256) >> 2;

  for (int kt = 0; kt < DMODEL / 32; ++kt) {
    const int k0 = kt * 32;
    float4 a0 = *(const float4*)&A[(m0 + r0) * DMODEL + k0 + c0];
    float4 a1 = *(const float4*)&A[(m0 + r0) * DMODEL + k0 + c0 + 4];
    float4 a2 = *(const float4*)&A[(m0 + r1) * DMODEL + k0 + c0];
    float4 a3 = *(const float4*)&A[(m0 + r1) * DMODEL + k0 + c0 + 4];
    bf16x8 b0 = *(const bf16x8*)&W[(n0 + r0) * DMODEL + k0 + c0];
    bf16x8 b1 = *(const bf16x8*)&W[(n0 + r1) * DMODEL + k0 + c0];
    __syncthreads();
    *(bf16x8*)&As[t * 8]        = cvt8(a0, a1);
    *(bf16x8*)&As[t * 8 + 2048] = cvt8(a2, a3);
    *(bf16x8*)&Bs[t * 8]        = b0;
    *(bf16x8*)&Bs[t * 8 + 2048] = b1;
    __syncthreads();
    bf16x8 af[4], bfr[4];
#pragma unroll
    for (int i = 0; i < 4; ++i)
      af[i] = *(const bf16x8*)&As[(wr * 64 + i * 16 + c) * 32 + g * 8];
#pragma unroll
    for (int j = 0; j < 4; ++j)
      bfr[j] = *(const bf16x8*)&Bs[(wc * 64 + j * 16 + c) * 32 + g * 8];
#pragma unroll
    for (int i = 0; i < 4; ++i)
#pragma unroll
      for (int j = 0; j < 4; ++j)
        acc[i][j] = MFMA16(af[i], bfr[j], acc[i][j]);
  }

  if (which == 2) {
    // V transposed epilogue: Vp[((b*H+h)*HD + hd)*S + s], 4 consecutive s
#pragma unroll
    for (int i = 0; i < 4; ++i) {
#pragma unroll
      for (int j = 0; j < 4; ++j) {
        const int n = n0 + wc * 64 + j * 16 + c;
        const int h = n >> 6, hd = n & 63;
        const float bn = bias[n];
        const int m = m0 + wr * 64 + i * 16 + g * 4;  // m..m+3 same batch, s consecutive
        const int bb = m >> 11, s = m & (S - 1);
        float v0 = acc[i][j][0] + bn, v1 = acc[i][j][1] + bn;
        float v2 = acc[i][j][2] + bn, v3 = acc[i][j][3] + bn;
        unsigned int w0, w1;
        asm("v_cvt_pk_bf16_f32 %0, %1, %2" : "=v"(w0) : "v"(v0), "v"(v1));
        asm("v_cvt_pk_bf16_f32 %0, %1, %2" : "=v"(w1) : "v"(v2), "v"(v3));
        uint2 pk2; pk2.x = w0; pk2.y = w1;
        *(uint2*)&dst[((bb * H + h) * HD + hd) * S + s] = pk2;
      }
    }
  } else {
#pragma unroll
    for (int i = 0; i < 4; ++i) {
#pragma unroll
      for (int j = 0; j < 4; ++j) {
        const int n = n0 + wc * 64 + j * 16 + c;
        const int h = n >> 6, hd = n & 63;
        const float bn = bias[n];
#pragma unroll
        for (int r = 0; r < 4; ++r) {
          const int m = m0 + wr * 64 + i * 16 + g * 4 + r;
          const int bb = m >> 11, s = m & (S - 1);
          dst[((bb * H + h) * S + s) * HD + hd] = f2b(acc[i][j][r] + bn);
        }
      }
    }
  }
}

// ---------------- output GEMM: Out = att @ Wo^T + bo (fp32 out) ----------------
__global__ __launch_bounds__(256) void out_gemm(
    const short* __restrict__ Am, const short* __restrict__ W,
    const float* __restrict__ bias, float* __restrict__ Out) {
  const int tm = blockIdx.x & 63;
  const int tn = blockIdx.x >> 6;
  const int m0 = tm * 128, n0 = tn * 128;
  const int t = threadIdx.x;
  const int lane = t & 63, w = t >> 6;
  const int g = lane >> 4, c = lane & 15;
  const int wr = w >> 1, wc = w & 1;

  __shared__ __align__(16) short As[128 * 32];
  __shared__ __align__(16) short Bs[128 * 32];

  f32x4 acc[4][4];
  const f32x4 fz = {0.f, 0.f, 0.f, 0.f};
#pragma unroll
  for (int i = 0; i < 4; ++i)
#pragma unroll
    for (int j = 0; j < 4; ++j) acc[i][j] = fz;

  const int r0 = t >> 2, c0 = (t & 3) * 8;
  const int r1 = (t + 256) >> 2;

  for (int kt = 0; kt < DMODEL / 32; ++kt) {
    const int k0 = kt * 32;
    bf16x8 a0 = *(const bf16x8*)&Am[(m0 + r0) * DMODEL + k0 + c0];
    bf16x8 a1 = *(const bf16x8*)&Am[(m0 + r1) * DMODEL + k0 + c0];
    bf16x8 b0 = *(const bf16x8*)&W[(n0 + r0) * DMODEL + k0 + c0];
    bf16x8 b1 = *(const bf16x8*)&W[(n0 + r1) * DMODEL + k0 + c0];
    __syncthreads();
    *(bf16x8*)&As[t * 8]        = a0;
    *(bf16x8*)&As[t * 8 + 2048] = a1;
    *(bf16x8*)&Bs[t * 8]        = b0;
    *(bf16x8*)&Bs[t * 8 + 2048] = b1;
    __syncthreads();
    bf16x8 af[4], bfr[4];
#pragma unroll
    for (int i = 0; i < 4; ++i)
      af[i] = *(const bf16x8*)&As[(wr * 64 + i * 16 + c) * 32 + g * 8];
#pragma unroll
    for (int j = 0; j < 4; ++j)
      bfr[j] = *(const bf16x8*)&Bs[(wc * 64 + j * 16 + c) * 32 + g * 8];
#pragma unroll
    for (int i = 0; i < 4; ++i)
#pragma unroll
      for (int j = 0; j < 4; ++j)
        acc[i][j] = MFMA16(af[i], bfr[j], acc[i][j]);
  }

#pragma unroll
  for (int i = 0; i < 4; ++i) {
#pragma unroll
    for (int j = 0; j < 4; ++j) {
      const int n = n0 + wc * 64 + j * 16 + c;
      const float bn = bias[n];
#pragma unroll
      for (int r = 0; r < 4; ++r) {
        const int m = m0 + wr * 64 + i * 16 + g * 4 + r;
        Out[m * DMODEL + n] = acc[i][j][r] + bn;
      }
    }
  }
}

// ---------------- flash attention, swapped-QK^T 32x32, no LDS, no barriers ----------------
// Per block: 4 independent waves x 32 q-rows. V is pre-transposed [B,H,HD,S]
// so PV A-frags come straight from global (L2-resident per XCD via swizzle).
__global__ __launch_bounds__(256, 2) void attn_kernel(
    const short* __restrict__ Qp, const short* __restrict__ Kp,
    const short* __restrict__ VTp, short* __restrict__ att) {
  const int bid = blockIdx.x;
  const int swz = (bid & 7) * 64 + (bid >> 3);  // 512 % 8 == 0: bijective
  const int qt = swz & 15;
  const int bh = swz >> 4;
  const int b = bh >> 3, h = bh & 7;
  const short* Q  = Qp  + bh * (S * HD);
  const short* K  = Kp  + bh * (S * HD);
  const short* VT = VTp + bh * (HD * S);

  const int t = threadIdx.x;
  const int lane = t & 63, w = t >> 6;
  const int l31 = lane & 31, hi = lane >> 5;
  const int q0 = qt * 128 + w * 32;

  // Q B-frags (col = q = lane&31, k = hd = ks*16 + hi*8 + j)
  bf16x8 qf[4];
#pragma unroll
  for (int ks = 0; ks < 4; ++ks)
    qf[ks] = *(const bf16x8*)&Q[(q0 + l31) * HD + ks * 16 + hi * 8];

  f32x16 o0, o1;  // o^T accumulators: col = q = lane&31, row = d
#pragma unroll
  for (int i = 0; i < 16; ++i) { o0[i] = 0.f; o1[i] = 0.f; }
  float mst = -1e30f, lst = 0.f;

  // prologue: K A-frags (row = kv, k = hd) and V^T A-frags (row = d, k = kv)
  bf16x8 kf[8], vf[8];
#pragma unroll
  for (int tt = 0; tt < 2; ++tt)
#pragma unroll
    for (int ks = 0; ks < 4; ++ks)
      kf[tt * 4 + ks] = *(const bf16x8*)&K[(tt * 32 + l31) * HD + ks * 16 + hi * 8];
#pragma unroll
  for (int dt = 0; dt < 2; ++dt)
#pragma unroll
    for (int ks = 0; ks < 4; ++ks)
      vf[dt * 4 + ks] = *(const bf16x8*)&VT[(dt * 32 + l31) * S + ks * 16 + hi * 8];

  const float SCL = 0.18033688011112042f;  // log2(e)/sqrt(HD)

  for (int kt = 0; kt < 32; ++kt) {
    // QK^T swapped: S^T[kv][q] (row = kv via (reg&3)+8*(reg>>2)+4*hi, col = q)
    f32x16 sa0, sa1;
#pragma unroll
    for (int i = 0; i < 16; ++i) { sa0[i] = 0.f; sa1[i] = 0.f; }
#pragma unroll
    for (int ks = 0; ks < 4; ++ks) {
      sa0 = MFMA32(kf[ks],     qf[ks], sa0);
      sa1 = MFMA32(kf[4 + ks], qf[ks], sa1);
    }

    // prefetch next K tile into the same regs (WAR after QK^T; covered by softmax+PV)
    const int kkn = ((kt < 31) ? (kt + 1) : 31) * 64;
#pragma unroll
    for (int tt = 0; tt < 2; ++tt)
#pragma unroll
      for (int ks = 0; ks < 4; ++ks)
        kf[tt * 4 + ks] = *(const bf16x8*)&K[(kkn + tt * 32 + l31) * HD + ks * 16 + hi * 8];

    // ---- in-register online softmax (per-lane q, kv split across hi) ----
    float tm[16];
#pragma unroll
    for (int i = 0; i < 16; ++i) tm[i] = fmaxf(sa0[i], sa1[i]);
#pragma unroll
    for (int i = 0; i < 8; ++i) tm[i] = fmaxf(tm[i], tm[i + 8]);
#pragma unroll
    for (int i = 0; i < 4; ++i) tm[i] = fmaxf(tm[i], tm[i + 4]);
    tm[0] = fmaxf(fmaxf(tm[0], tm[2]), fmaxf(tm[1], tm[3]));
    const float mx = fmaxf(tm[0], __shfl_xor(tm[0], 32, 64));
    const float mxs = mx * SCL;

    if (!__all(mxs - mst <= 8.0f)) {  // defer-max (T13)
      const float mn = fmaxf(mst, mxs);
      const float corr = exp2f(mst - mn);
      lst *= corr;
#pragma unroll
      for (int i = 0; i < 16; ++i) { o0[i] *= corr; o1[i] *= corr; }
      mst = mn;
    }

#pragma unroll
    for (int i = 0; i < 16; ++i) {
      sa0[i] = exp2f(__builtin_fmaf(sa0[i], SCL, -mst));
      sa1[i] = exp2f(__builtin_fmaf(sa1[i], SCL, -mst));
    }
    float ts[16];
#pragma unroll
    for (int i = 0; i < 16; ++i) ts[i] = sa0[i] + sa1[i];
#pragma unroll
    for (int i = 0; i < 8; ++i) ts[i] = ts[i] + ts[i + 8];
#pragma unroll
    for (int i = 0; i < 4; ++i) ts[i] = ts[i] + ts[i + 4];
    ts[0] = (ts[0] + ts[2]) + (ts[1] + ts[3]);
    lst += ts[0] + __shfl_xor(ts[0], 32, 64);

    // ---- P -> bf16 words; permlane32_swap assembles PV B-frags (T12, verified R3) ----
    unsigned int wrd0[8], wrd1[8];
#pragma unroll
    for (int i = 0; i < 8; ++i) {
      asm("v_cvt_pk_bf16_f32 %0, %1, %2" : "=v"(wrd0[i]) : "v"(sa0[2 * i]), "v"(sa0[2 * i + 1]));
      asm("v_cvt_pk_bf16_f32 %0, %1, %2" : "=v"(wrd1[i]) : "v"(sa1[2 * i]), "v"(sa1[2 * i + 1]));
    }

    // PV: o^T += V^T @ P  (A = V^T frags from global, B = P in-register)
#pragma unroll
    for (int ks = 0; ks < 4; ++ks) {
      const int i0 = (ks & 1) * 4;
      unsigned int a0 = (ks < 2) ? wrd0[i0 + 0] : wrd1[i0 + 0];
      unsigned int b0 = (ks < 2) ? wrd0[i0 + 2] : wrd1[i0 + 2];
      unsigned int a1 = (ks < 2) ? wrd0[i0 + 1] : wrd1[i0 + 1];
      unsigned int b1 = (ks < 2) ? wrd0[i0 + 3] : wrd1[i0 + 3];
      asm("v_permlane32_swap_b32 %0, %1" : "+v"(a0), "+v"(b0));
      asm("v_permlane32_swap_b32 %0, %1" : "+v"(a1), "+v"(b1));
      u32x4 fw;
      fw[0] = a0; fw[1] = a1; fw[2] = b0; fw[3] = b1;
      const bf16x8 pfrag = __builtin_bit_cast(bf16x8, fw);
      o0 = MFMA32(vf[ks],     pfrag, o0);
      o1 = MFMA32(vf[4 + ks], pfrag, o1);
    }

    // prefetch next V^T tile (WAR after PV; covered by next QK^T + softmax)
#pragma unroll
    for (int dt = 0; dt < 2; ++dt)
#pragma unroll
      for (int ks = 0; ks < 4; ++ks)
        vf[dt * 4 + ks] = *(const bf16x8*)&VT[(dt * 32 + l31) * S + kkn + ks * 16 + hi * 8];
  }

  // epilogue: att[b*S + q][h*HD + d] = o^T / l  (q = lane&31; d = (reg&3)+8*(reg>>2)+4*hi+32*dt)
  const float inv = 1.0f / lst;
  short* arow = att + (b * S + q0 + l31) * DMODEL + h * HD;
#pragma unroll
  for (int dt = 0; dt < 2; ++dt) {
#pragma unroll
    for (int rr = 0; rr < 4; ++rr) {
      float v0 = (dt ? o1[4 * rr + 0] : o0[4 * rr + 0]) * inv;
      float v1 = (dt ? o1[4 * rr + 1] : o0[4 * rr + 1]) * inv;
      float v2 = (dt ? o1[4 * rr + 2] : o0[4 * rr + 2]) * inv;
      float v3 = (dt ? o1[4 * rr + 3] : o0[4 * rr + 3]) * inv;
      unsigned int w0, w1;
      asm("v_cvt_pk_bf16_f32 %0, %1, %2" : "=v"(w0) : "v"(v0), "v"(v1));
      asm("v_cvt_pk_bf16_f32 %0, %1, %2" : "=v"(w1) : "v"(v2), "v"(v3));
      uint2 pk2;
      pk2.x = w0; pk2.y = w1;
      *(uint2*)&arow[dt * 32 + rr * 8 + hi * 4] = pk2;
    }
  }
}

extern "C" void kernel_launch(void* const* d_in, const int* in_sizes, int n_in,
                              void* d_out, int out_size, void* d_ws, size_t ws_size,
                              hipStream_t stream) {
  const float* query = (const float*)d_in[0];
  const float* key_  = (const float*)d_in[1];
  const float* value = (const float*)d_in[2];
  const float* Wq = (const float*)d_in[3];
  const float* bq = (const float*)d_in[4];
  const float* Wk = (const float*)d_in[5];
  const float* bk = (const float*)d_in[6];
  const float* Wv = (const float*)d_in[7];
  const float* bv = (const float*)d_in[8];
  const float* Wo = (const float*)d_in[9];
  const float* bo = (const float*)d_in[10];
  float* out = (float*)d_out;

  char* ws = (char*)d_ws;
  const size_t WB_BYTES  = (size_t)4 * DMODEL * DMODEL * 2;  // 2 MiB
  const size_t MAT_BYTES = (size_t)M * DMODEL * 2;           // 8 MiB each
  short* Wb  = (short*)ws;
  short* Qp  = (short*)(ws + WB_BYTES);
  short* Kp  = (short*)(ws + WB_BYTES + MAT_BYTES);
  short* Vp  = (short*)(ws + WB_BYTES + 2 * MAT_BYTES);   // transposed [B,H,HD,S]
  short* att = (short*)(ws + WB_BYTES + 3 * MAT_BYTES);

  convert_w<<<dim3(128, 4), 256, 0, stream>>>(Wq, Wk, Wv, Wo, Wb);
  proj_gemm<<<dim3(256, 3), 256, 0, stream>>>(query, key_, value, Wb, bq, bk, bv, Qp, Kp, Vp);
  attn_kernel<<<dim3(512), 256, 0, stream>>>(Qp, Kp, Vp, att);
  out_gemm<<<dim3(256), 256, 0, stream>>>(att, Wb + 3 * DMODEL * DMODEL, bo, out);
}

// Round 5
// 127.320 us; speedup vs baseline: 1.4096x; 1.4096x over previous
//
#include <hip/hip_runtime.h>
#include <hip/hip_bf16.h>

typedef __attribute__((ext_vector_type(8))) short bf16x8;
typedef __attribute__((ext_vector_type(4))) float f32x4;
typedef __attribute__((ext_vector_type(16))) float f32x16;
typedef __attribute__((ext_vector_type(4))) unsigned int u32x4;

#define MFMA16(a, b, c) __builtin_amdgcn_mfma_f32_16x16x32_bf16((a), (b), (c), 0, 0, 0)
#define MFMA32(a, b, c) __builtin_amdgcn_mfma_f32_32x32x16_bf16((a), (b), (c), 0, 0, 0)

static constexpr int BATCH = 4, S = 2048, DMODEL = 512, H = 8, HD = 64;
static constexpr int M = BATCH * S;  // 8192

// round-to-nearest-even f32 -> bf16 (bit trick; inputs finite)
__device__ __forceinline__ short f2b(float f) {
  unsigned int u = __builtin_bit_cast(unsigned int, f);
  unsigned int r = (u + 0x7fffu + ((u >> 16) & 1u)) >> 16;
  return (short)r;
}

__device__ __forceinline__ bf16x8 cvt8(const float4& a, const float4& b) {
  bf16x8 r;
  r[0] = f2b(a.x); r[1] = f2b(a.y); r[2] = f2b(a.z); r[3] = f2b(a.w);
  r[4] = f2b(b.x); r[5] = f2b(b.y); r[6] = f2b(b.z); r[7] = f2b(b.w);
  return r;
}

// async global -> LDS, 16 bytes/lane. LDS dest: wave-uniform base + lane*16.
__device__ __forceinline__ void glds16(const void* g, void* l) {
  __builtin_amdgcn_global_load_lds(
      (const __attribute__((address_space(1))) unsigned int*)g,
      (__attribute__((address_space(3))) unsigned int*)l, 16, 0, 0);
}

// ---------------- weight fp32 -> bf16 ----------------
__global__ __launch_bounds__(256) void convert_w(
    const float* __restrict__ Wq, const float* __restrict__ Wk,
    const float* __restrict__ Wv, const float* __restrict__ Wo,
    short* __restrict__ Wb) {
  const float* src = (blockIdx.y == 0) ? Wq : (blockIdx.y == 1) ? Wk
                   : (blockIdx.y == 2) ? Wv : Wo;
  short* dst = Wb + blockIdx.y * (DMODEL * DMODEL);
  int i = (blockIdx.x * 256 + threadIdx.x) * 8;
  float4 a = *(const float4*)&src[i];
  float4 b = *(const float4*)&src[i + 4];
  *(bf16x8*)&dst[i] = cvt8(a, b);
}

// ---------------- fused Q/K/V projection: C = A @ W^T + b ----------------
// Q,K scatter to [B,H,S,HD]; V scatters TRANSPOSED to [B,H,HD,S].
__global__ __launch_bounds__(256) void proj_gemm(
    const float* __restrict__ Aq, const float* __restrict__ Ak, const float* __restrict__ Av,
    const short* __restrict__ Wb,
    const float* __restrict__ bq, const float* __restrict__ bk, const float* __restrict__ bv,
    short* __restrict__ Qp, short* __restrict__ Kp, short* __restrict__ Vp) {
  const int which = blockIdx.y;
  const float* A    = (which == 0) ? Aq : (which == 1) ? Ak : Av;
  const short* W    = Wb + which * (DMODEL * DMODEL);
  const float* bias = (which == 0) ? bq : (which == 1) ? bk : bv;
  short* dst        = (which == 0) ? Qp : (which == 1) ? Kp : Vp;

  const int tm = blockIdx.x & 63;
  const int tn = blockIdx.x >> 6;
  const int m0 = tm * 128, n0 = tn * 128;
  const int t = threadIdx.x;
  const int lane = t & 63, w = t >> 6;
  const int g = lane >> 4, c = lane & 15;
  const int wr = w >> 1, wc = w & 1;

  __shared__ __align__(16) short As[128 * 32];
  __shared__ __align__(16) short Bs[128 * 32];

  f32x4 acc[4][4];
  const f32x4 fz = {0.f, 0.f, 0.f, 0.f};
#pragma unroll
  for (int i = 0; i < 4; ++i)
#pragma unroll
    for (int j = 0; j < 4; ++j) acc[i][j] = fz;

  const int r0 = t >> 2, c0 = (t & 3) * 8;
  const int r1 = (t + 256) >> 2;

  for (int kt = 0; kt < DMODEL / 32; ++kt) {
    const int k0 = kt * 32;
    float4 a0 = *(const float4*)&A[(m0 + r0) * DMODEL + k0 + c0];
    float4 a1 = *(const float4*)&A[(m0 + r0) * DMODEL + k0 + c0 + 4];
    float4 a2 = *(const float4*)&A[(m0 + r1) * DMODEL + k0 + c0];
    float4 a3 = *(const float4*)&A[(m0 + r1) * DMODEL + k0 + c0 + 4];
    bf16x8 b0 = *(const bf16x8*)&W[(n0 + r0) * DMODEL + k0 + c0];
    bf16x8 b1 = *(const bf16x8*)&W[(n0 + r1) * DMODEL + k0 + c0];
    __syncthreads();
    *(bf16x8*)&As[t * 8]        = cvt8(a0, a1);
    *(bf16x8*)&As[t * 8 + 2048] = cvt8(a2, a3);
    *(bf16x8*)&Bs[t * 8]        = b0;
    *(bf16x8*)&Bs[t * 8 + 2048] = b1;
    __syncthreads();
    bf16x8 af[4], bfr[4];
#pragma unroll
    for (int i = 0; i < 4; ++i)
      af[i] = *(const bf16x8*)&As[(wr * 64 + i * 16 + c) * 32 + g * 8];
#pragma unroll
    for (int j = 0; j < 4; ++j)
      bfr[j] = *(const bf16x8*)&Bs[(wc * 64 + j * 16 + c) * 32 + g * 8];
#pragma unroll
    for (int i = 0; i < 4; ++i)
#pragma unroll
      for (int j = 0; j < 4; ++j)
        acc[i][j] = MFMA16(af[i], bfr[j], acc[i][j]);
  }

  if (which == 2) {
    // V transposed epilogue: Vp[((b*H+h)*HD + hd)*S + s], 4 consecutive s
#pragma unroll
    for (int i = 0; i < 4; ++i) {
#pragma unroll
      for (int j = 0; j < 4; ++j) {
        const int n = n0 + wc * 64 + j * 16 + c;
        const int h = n >> 6, hd = n & 63;
        const float bn = bias[n];
        const int m = m0 + wr * 64 + i * 16 + g * 4;
        const int bb = m >> 11, s = m & (S - 1);
        float v0 = acc[i][j][0] + bn, v1 = acc[i][j][1] + bn;
        float v2 = acc[i][j][2] + bn, v3 = acc[i][j][3] + bn;
        unsigned int w0, w1;
        asm("v_cvt_pk_bf16_f32 %0, %1, %2" : "=v"(w0) : "v"(v0), "v"(v1));
        asm("v_cvt_pk_bf16_f32 %0, %1, %2" : "=v"(w1) : "v"(v2), "v"(v3));
        uint2 pk2; pk2.x = w0; pk2.y = w1;
        *(uint2*)&dst[((bb * H + h) * HD + hd) * S + s] = pk2;
      }
    }
  } else {
#pragma unroll
    for (int i = 0; i < 4; ++i) {
#pragma unroll
      for (int j = 0; j < 4; ++j) {
        const int n = n0 + wc * 64 + j * 16 + c;
        const int h = n >> 6, hd = n & 63;
        const float bn = bias[n];
#pragma unroll
        for (int r = 0; r < 4; ++r) {
          const int m = m0 + wr * 64 + i * 16 + g * 4 + r;
          const int bb = m >> 11, s = m & (S - 1);
          dst[((bb * H + h) * S + s) * HD + hd] = f2b(acc[i][j][r] + bn);
        }
      }
    }
  }
}

// ---------------- output GEMM: Out = att @ Wo^T + bo (fp32 out) ----------------
__global__ __launch_bounds__(256) void out_gemm(
    const short* __restrict__ Am, const short* __restrict__ W,
    const float* __restrict__ bias, float* __restrict__ Out) {
  const int tm = blockIdx.x & 63;
  const int tn = blockIdx.x >> 6;
  const int m0 = tm * 128, n0 = tn * 128;
  const int t = threadIdx.x;
  const int lane = t & 63, w = t >> 6;
  const int g = lane >> 4, c = lane & 15;
  const int wr = w >> 1, wc = w & 1;

  __shared__ __align__(16) short As[128 * 32];
  __shared__ __align__(16) short Bs[128 * 32];

  f32x4 acc[4][4];
  const f32x4 fz = {0.f, 0.f, 0.f, 0.f};
#pragma unroll
  for (int i = 0; i < 4; ++i)
#pragma unroll
    for (int j = 0; j < 4; ++j) acc[i][j] = fz;

  const int r0 = t >> 2, c0 = (t & 3) * 8;
  const int r1 = (t + 256) >> 2;

  for (int kt = 0; kt < DMODEL / 32; ++kt) {
    const int k0 = kt * 32;
    bf16x8 a0 = *(const bf16x8*)&Am[(m0 + r0) * DMODEL + k0 + c0];
    bf16x8 a1 = *(const bf16x8*)&Am[(m0 + r1) * DMODEL + k0 + c0];
    bf16x8 b0 = *(const bf16x8*)&W[(n0 + r0) * DMODEL + k0 + c0];
    bf16x8 b1 = *(const bf16x8*)&W[(n0 + r1) * DMODEL + k0 + c0];
    __syncthreads();
    *(bf16x8*)&As[t * 8]        = a0;
    *(bf16x8*)&As[t * 8 + 2048] = a1;
    *(bf16x8*)&Bs[t * 8]        = b0;
    *(bf16x8*)&Bs[t * 8 + 2048] = b1;
    __syncthreads();
    bf16x8 af[4], bfr[4];
#pragma unroll
    for (int i = 0; i < 4; ++i)
      af[i] = *(const bf16x8*)&As[(wr * 64 + i * 16 + c) * 32 + g * 8];
#pragma unroll
    for (int j = 0; j < 4; ++j)
      bfr[j] = *(const bf16x8*)&Bs[(wc * 64 + j * 16 + c) * 32 + g * 8];
#pragma unroll
    for (int i = 0; i < 4; ++i)
#pragma unroll
      for (int j = 0; j < 4; ++j)
        acc[i][j] = MFMA16(af[i], bfr[j], acc[i][j]);
  }

#pragma unroll
  for (int i = 0; i < 4; ++i) {
#pragma unroll
    for (int j = 0; j < 4; ++j) {
      const int n = n0 + wc * 64 + j * 16 + c;
      const float bn = bias[n];
#pragma unroll
      for (int r = 0; r < 4; ++r) {
        const int m = m0 + wr * 64 + i * 16 + g * 4 + r;
        Out[m * DMODEL + n] = acc[i][j][r] + bn;
      }
    }
  }
}

// ---------------- flash attention: swapped-QK^T 32x32, LDS-staged K/V via gload_lds ----------------
// 4 waves x 32 q-rows = 128-q blocks. K tile [64 kv][64 hd] and V^T tile [64 d][64 kv]
// staged cooperatively (once per block) with inverse-swizzled source (rule #21);
// frag ds_reads use byte ^= (row&7)<<4 to break the 128B-pitch bank conflict.
__global__ __launch_bounds__(256, 2) void attn_kernel(
    const short* __restrict__ Qp, const short* __restrict__ Kp,
    const short* __restrict__ VTp, short* __restrict__ att) {
  const int bid = blockIdx.x;
  const int swzb = (bid & 7) * 64 + (bid >> 3);  // 512 % 8 == 0: bijective
  const int qt = swzb & 15;
  const int bh = swzb >> 4;
  const int b = bh >> 3, h = bh & 7;
  const short* Q  = Qp  + bh * (S * HD);
  const char*  Kg = (const char*)(Kp  + bh * (S * HD));
  const char*  Vg = (const char*)(VTp + bh * (HD * S));

  const int t = threadIdx.x;
  const int lane = t & 63, w = t >> 6;
  const int l31 = lane & 31, hi = lane >> 5;
  const int q0 = qt * 128 + w * 32;

  __shared__ __align__(16) char smem[2 * 16384];  // [buf][K 8KB | V^T 8KB]

  // per-lane staging source offsets (inverse-swizzled so linear LDS + swizzled read = correct)
  const int rowi = lane >> 3;            // 0..7 == row&7 for this lane's rows
  const int swzs = ((lane & 7) * 16) ^ (rowi << 4);
  // K rows contiguous (row stride 128B): tile byte = row*128 + swizzled-inrow
  const char* ksrc0 = Kg + (w * 16 + rowi) * 128 + swzs;          // + kt*8192
  const char* ksrc1 = ksrc0 + 8 * 128;
  // V^T rows strided 4096B; within-row kv offset kt*128
  const char* vsrc0 = Vg + (w * 16 + rowi) * 4096 + swzs;         // + kt*128
  const char* vsrc1 = vsrc0 + 8 * 4096;

  // Q B-frags (col = q = lane&31, k = hd = ks*16 + hi*8 + j)
  bf16x8 qf[4];
#pragma unroll
  for (int ks = 0; ks < 4; ++ks)
    qf[ks] = *(const bf16x8*)&Q[(q0 + l31) * HD + ks * 16 + hi * 8];

  f32x16 o0, o1;  // o^T accumulators: col = q, row = d
#pragma unroll
  for (int i = 0; i < 16; ++i) { o0[i] = 0.f; o1[i] = 0.f; }
  float mst = -1e30f, lst = 0.f;

  // prologue: stage tile 0 into buf 0
  glds16(ksrc0, smem + w * 2048);
  glds16(ksrc1, smem + w * 2048 + 1024);
  glds16(vsrc0, smem + 8192 + w * 2048);
  glds16(vsrc1, smem + 8192 + w * 2048 + 1024);
  __syncthreads();

  const float SCL = 0.18033688011112042f;  // log2(e)/sqrt(HD)
  const int fswz = (l31 & 7) << 4;         // frag-read swizzle

  for (int kt = 0; kt < 32; ++kt) {
    const int cb = (kt & 1) * 16384;

    // issue staging of tile kt+1 into the other buffer (async; drains at __syncthreads)
    if (kt < 31) {
      char* nb = smem + (cb ^ 16384);
      const size_t ko = (size_t)(kt + 1) * 8192;
      const size_t vo = (size_t)(kt + 1) * 128;
      glds16(ksrc0 + ko, nb + w * 2048);
      glds16(ksrc1 + ko, nb + w * 2048 + 1024);
      glds16(vsrc0 + vo, nb + 8192 + w * 2048);
      glds16(vsrc1 + vo, nb + 8192 + w * 2048 + 1024);
    }

    // QK^T swapped: S^T[kv][q]; K A-frags from LDS (swizzled read)
    f32x16 sa0, sa1;
#pragma unroll
    for (int i = 0; i < 16; ++i) { sa0[i] = 0.f; sa1[i] = 0.f; }
#pragma unroll
    for (int ks = 0; ks < 4; ++ks) {
      const int col = (ks * 32 + hi * 16) ^ fswz;
      const bf16x8 k0 = *(const bf16x8*)&smem[cb + l31 * 128 + col];
      const bf16x8 k1 = *(const bf16x8*)&smem[cb + (32 + l31) * 128 + col];
      sa0 = MFMA32(k0, qf[ks], sa0);
      sa1 = MFMA32(k1, qf[ks], sa1);
    }

    // ---- in-register online softmax (per-lane q, kv split across hi) ----
    float tmx[16];
#pragma unroll
    for (int i = 0; i < 16; ++i) tmx[i] = fmaxf(sa0[i], sa1[i]);
#pragma unroll
    for (int i = 0; i < 8; ++i) tmx[i] = fmaxf(tmx[i], tmx[i + 8]);
#pragma unroll
    for (int i = 0; i < 4; ++i) tmx[i] = fmaxf(tmx[i], tmx[i + 4]);
    tmx[0] = fmaxf(fmaxf(tmx[0], tmx[2]), fmaxf(tmx[1], tmx[3]));
    const float mx = fmaxf(tmx[0], __shfl_xor(tmx[0], 32, 64));
    const float mxs = mx * SCL;

    if (!__all(mxs - mst <= 8.0f)) {  // defer-max (T13)
      const float mn = fmaxf(mst, mxs);
      const float corr = exp2f(mst - mn);
      lst *= corr;
#pragma unroll
      for (int i = 0; i < 16; ++i) { o0[i] *= corr; o1[i] *= corr; }
      mst = mn;
    }

#pragma unroll
    for (int i = 0; i < 16; ++i) {
      sa0[i] = exp2f(__builtin_fmaf(sa0[i], SCL, -mst));
      sa1[i] = exp2f(__builtin_fmaf(sa1[i], SCL, -mst));
    }
    float tsm[16];
#pragma unroll
    for (int i = 0; i < 16; ++i) tsm[i] = sa0[i] + sa1[i];
#pragma unroll
    for (int i = 0; i < 8; ++i) tsm[i] = tsm[i] + tsm[i + 8];
#pragma unroll
    for (int i = 0; i < 4; ++i) tsm[i] = tsm[i] + tsm[i + 4];
    tsm[0] = (tsm[0] + tsm[2]) + (tsm[1] + tsm[3]);
    lst += tsm[0] + __shfl_xor(tsm[0], 32, 64);

    // ---- P -> bf16 words; permlane32_swap assembles PV B-frags (T12, verified R3) ----
    unsigned int wrd0[8], wrd1[8];
#pragma unroll
    for (int i = 0; i < 8; ++i) {
      asm("v_cvt_pk_bf16_f32 %0, %1, %2" : "=v"(wrd0[i]) : "v"(sa0[2 * i]), "v"(sa0[2 * i + 1]));
      asm("v_cvt_pk_bf16_f32 %0, %1, %2" : "=v"(wrd1[i]) : "v"(sa1[2 * i]), "v"(sa1[2 * i + 1]));
    }

    // PV: o^T += V^T @ P  (A = V^T frags from LDS swizzled, B = P in-register)
#pragma unroll
    for (int ks = 0; ks < 4; ++ks) {
      const int i0 = (ks & 1) * 4;
      unsigned int a0 = (ks < 2) ? wrd0[i0 + 0] : wrd1[i0 + 0];
      unsigned int b0 = (ks < 2) ? wrd0[i0 + 2] : wrd1[i0 + 2];
      unsigned int a1 = (ks < 2) ? wrd0[i0 + 1] : wrd1[i0 + 1];
      unsigned int b1 = (ks < 2) ? wrd0[i0 + 3] : wrd1[i0 + 3];
      asm("v_permlane32_swap_b32 %0, %1" : "+v"(a0), "+v"(b0));
      asm("v_permlane32_swap_b32 %0, %1" : "+v"(a1), "+v"(b1));
      u32x4 fw;
      fw[0] = a0; fw[1] = a1; fw[2] = b0; fw[3] = b1;
      const bf16x8 pfrag = __builtin_bit_cast(bf16x8, fw);
      const int col = (ks * 32 + hi * 16) ^ fswz;
      const bf16x8 va0 = *(const bf16x8*)&smem[cb + 8192 + l31 * 128 + col];
      const bf16x8 va1 = *(const bf16x8*)&smem[cb + 8192 + (32 + l31) * 128 + col];
      o0 = MFMA32(va0, pfrag, o0);
      o1 = MFMA32(va1, pfrag, o1);
    }

    // vmcnt(0)+lgkmcnt(0)+barrier: staging landed, all frag reads done
    __syncthreads();
  }

  // epilogue: att[b*S + q][h*HD + d] = o^T / l  (q = lane&31; d = (reg&3)+8*(reg>>2)+4*hi+32*dt)
  const float inv = 1.0f / lst;
  short* arow = att + (b * S + q0 + l31) * DMODEL + h * HD;
#pragma unroll
  for (int dt = 0; dt < 2; ++dt) {
#pragma unroll
    for (int rr = 0; rr < 4; ++rr) {
      float v0 = (dt ? o1[4 * rr + 0] : o0[4 * rr + 0]) * inv;
      float v1 = (dt ? o1[4 * rr + 1] : o0[4 * rr + 1]) * inv;
      float v2 = (dt ? o1[4 * rr + 2] : o0[4 * rr + 2]) * inv;
      float v3 = (dt ? o1[4 * rr + 3] : o0[4 * rr + 3]) * inv;
      unsigned int w0, w1;
      asm("v_cvt_pk_bf16_f32 %0, %1, %2" : "=v"(w0) : "v"(v0), "v"(v1));
      asm("v_cvt_pk_bf16_f32 %0, %1, %2" : "=v"(w1) : "v"(v2), "v"(v3));
      uint2 pk2;
      pk2.x = w0; pk2.y = w1;
      *(uint2*)&arow[dt * 32 + rr * 8 + hi * 4] = pk2;
    }
  }
}

extern "C" void kernel_launch(void* const* d_in, const int* in_sizes, int n_in,
                              void* d_out, int out_size, void* d_ws, size_t ws_size,
                              hipStream_t stream) {
  const float* query = (const float*)d_in[0];
  const float* key_  = (const float*)d_in[1];
  const float* value = (const float*)d_in[2];
  const float* Wq = (const float*)d_in[3];
  const float* bq = (const float*)d_in[4];
  const float* Wk = (const float*)d_in[5];
  const float* bk = (const float*)d_in[6];
  const float* Wv = (const float*)d_in[7];
  const float* bv = (const float*)d_in[8];
  const float* Wo = (const float*)d_in[9];
  const float* bo = (const float*)d_in[10];
  float* out = (float*)d_out;

  char* ws = (char*)d_ws;
  const size_t WB_BYTES  = (size_t)4 * DMODEL * DMODEL * 2;  // 2 MiB
  const size_t MAT_BYTES = (size_t)M * DMODEL * 2;           // 8 MiB each
  short* Wb  = (short*)ws;
  short* Qp  = (short*)(ws + WB_BYTES);
  short* Kp  = (short*)(ws + WB_BYTES + MAT_BYTES);
  short* Vp  = (short*)(ws + WB_BYTES + 2 * MAT_BYTES);   // transposed [B,H,HD,S]
  short* att = (short*)(ws + WB_BYTES + 3 * MAT_BYTES);

  convert_w<<<dim3(128, 4), 256, 0, stream>>>(Wq, Wk, Wv, Wo, Wb);
  proj_gemm<<<dim3(256, 3), 256, 0, stream>>>(query, key_, value, Wb, bq, bk, bv, Qp, Kp, Vp);
  attn_kernel<<<dim3(512), 256, 0, stream>>>(Qp, Kp, Vp, att);
  out_gemm<<<dim3(256), 256, 0, stream>>>(att, Wb + 3 * DMODEL * DMODEL, bo, out);
}

// Round 6
// 123.080 us; speedup vs baseline: 1.4582x; 1.0344x over previous
//
#include <hip/hip_runtime.h>
#include <hip/hip_bf16.h>

typedef __attribute__((ext_vector_type(8))) short bf16x8;
typedef __attribute__((ext_vector_type(4))) float f32x4;
typedef __attribute__((ext_vector_type(16))) float f32x16;
typedef __attribute__((ext_vector_type(4))) unsigned int u32x4;

#define MFMA16(a, b, c) __builtin_amdgcn_mfma_f32_16x16x32_bf16((a), (b), (c), 0, 0, 0)
#define MFMA32(a, b, c) __builtin_amdgcn_mfma_f32_32x32x16_bf16((a), (b), (c), 0, 0, 0)

static constexpr int BATCH = 4, S = 2048, DMODEL = 512, H = 8, HD = 64;
static constexpr int M = BATCH * S;  // 8192
static constexpr int LP = 40;        // GEMM LDS pitch in shorts (80B): 2-way banks, 16B-aligned

__device__ __forceinline__ float fmax3(float a, float b, float c) {
  return fmaxf(fmaxf(a, b), c);  // clang fuses to v_max3_f32
}

// round-to-nearest-even f32 -> bf16 (bit trick; inputs finite)
__device__ __forceinline__ short f2b(float f) {
  unsigned int u = __builtin_bit_cast(unsigned int, f);
  unsigned int r = (u + 0x7fffu + ((u >> 16) & 1u)) >> 16;
  return (short)r;
}

__device__ __forceinline__ bf16x8 cvt8(const float4& a, const float4& b) {
  bf16x8 r;
  r[0] = f2b(a.x); r[1] = f2b(a.y); r[2] = f2b(a.z); r[3] = f2b(a.w);
  r[4] = f2b(b.x); r[5] = f2b(b.y); r[6] = f2b(b.z); r[7] = f2b(b.w);
  return r;
}

// async global -> LDS, 16 bytes/lane. LDS dest: wave-uniform base + lane*16.
__device__ __forceinline__ void glds16(const void* g, void* l) {
  __builtin_amdgcn_global_load_lds(
      (const __attribute__((address_space(1))) unsigned int*)g,
      (__attribute__((address_space(3))) unsigned int*)l, 16, 0, 0);
}

// ---------------- weight fp32 -> bf16 ----------------
__global__ __launch_bounds__(256) void convert_w(
    const float* __restrict__ Wq, const float* __restrict__ Wk,
    const float* __restrict__ Wv, const float* __restrict__ Wo,
    short* __restrict__ Wb) {
  const float* src = (blockIdx.y == 0) ? Wq : (blockIdx.y == 1) ? Wk
                   : (blockIdx.y == 2) ? Wv : Wo;
  short* dst = Wb + blockIdx.y * (DMODEL * DMODEL);
  int i = (blockIdx.x * 256 + threadIdx.x) * 8;
  float4 a = *(const float4*)&src[i];
  float4 b = *(const float4*)&src[i + 4];
  *(bf16x8*)&dst[i] = cvt8(a, b);
}

// ---------------- fused Q/K/V projection: C = A @ W^T + b ----------------
// Q,K scatter to [B,H,S,HD]; V scatters TRANSPOSED to [B,H,HD,S] via an
// LDS-transpose epilogue (coalesced 64B stores).
__global__ __launch_bounds__(256) void proj_gemm(
    const float* __restrict__ Aq, const float* __restrict__ Ak, const float* __restrict__ Av,
    const short* __restrict__ Wb,
    const float* __restrict__ bq, const float* __restrict__ bk, const float* __restrict__ bv,
    short* __restrict__ Qp, short* __restrict__ Kp, short* __restrict__ Vp) {
  const int which = blockIdx.y;
  const float* A    = (which == 0) ? Aq : (which == 1) ? Ak : Av;
  const short* W    = Wb + which * (DMODEL * DMODEL);
  const float* bias = (which == 0) ? bq : (which == 1) ? bk : bv;
  short* dst        = (which == 0) ? Qp : (which == 1) ? Kp : Vp;

  const int tm = blockIdx.x & 63;
  const int tn = blockIdx.x >> 6;
  const int m0 = tm * 128, n0 = tn * 128;
  const int t = threadIdx.x;
  const int lane = t & 63, w = t >> 6;
  const int g = lane >> 4, c = lane & 15;
  const int wr = w >> 1, wc = w & 1;

  __shared__ __align__(16) short SM[2 * 128 * LP];  // As | Bs; reused as Cs in epilogue
  short* As = SM;
  short* Bs = SM + 128 * LP;

  f32x4 acc[4][4];
  const f32x4 fz = {0.f, 0.f, 0.f, 0.f};
#pragma unroll
  for (int i = 0; i < 4; ++i)
#pragma unroll
    for (int j = 0; j < 4; ++j) acc[i][j] = fz;

  const int r0 = t >> 2, c0 = (t & 3) * 8;
  const int r1 = r0 + 64;

  for (int kt = 0; kt < DMODEL / 32; ++kt) {
    const int k0 = kt * 32;
    float4 a0 = *(const float4*)&A[(m0 + r0) * DMODEL + k0 + c0];
    float4 a1 = *(const float4*)&A[(m0 + r0) * DMODEL + k0 + c0 + 4];
    float4 a2 = *(const float4*)&A[(m0 + r1) * DMODEL + k0 + c0];
    float4 a3 = *(const float4*)&A[(m0 + r1) * DMODEL + k0 + c0 + 4];
    bf16x8 b0 = *(const bf16x8*)&W[(n0 + r0) * DMODEL + k0 + c0];
    bf16x8 b1 = *(const bf16x8*)&W[(n0 + r1) * DMODEL + k0 + c0];
    __syncthreads();
    *(bf16x8*)&As[r0 * LP + c0] = cvt8(a0, a1);
    *(bf16x8*)&As[r1 * LP + c0] = cvt8(a2, a3);
    *(bf16x8*)&Bs[r0 * LP + c0] = b0;
    *(bf16x8*)&Bs[r1 * LP + c0] = b1;
    __syncthreads();
    bf16x8 af[4], bfr[4];
#pragma unroll
    for (int i = 0; i < 4; ++i)
      af[i] = *(const bf16x8*)&As[(wr * 64 + i * 16 + c) * LP + g * 8];
#pragma unroll
    for (int j = 0; j < 4; ++j)
      bfr[j] = *(const bf16x8*)&Bs[(wc * 64 + j * 16 + c) * LP + g * 8];
#pragma unroll
    for (int i = 0; i < 4; ++i)
#pragma unroll
      for (int j = 0; j < 4; ++j)
        acc[i][j] = MFMA16(af[i], bfr[j], acc[i][j]);
  }

  if (which == 2) {
    // transpose epilogue through LDS: Cs[n_loc 0..127][m_loc 0..63] pitch 72
    short* Cs = SM;
    __syncthreads();  // all frag reads done before overwrite
#pragma unroll 1
    for (int ph = 0; ph < 2; ++ph) {
      if (wr == ph) {
#pragma unroll
        for (int i = 0; i < 4; ++i) {
#pragma unroll
          for (int j = 0; j < 4; ++j) {
            const int nl = wc * 64 + j * 16 + c;
            const float bn = bias[n0 + nl];
            short4 pk;
            pk.x = f2b(acc[i][j][0] + bn);
            pk.y = f2b(acc[i][j][1] + bn);
            pk.z = f2b(acc[i][j][2] + bn);
            pk.w = f2b(acc[i][j][3] + bn);
            *(short4*)&Cs[nl * 72 + i * 16 + g * 4] = pk;
          }
        }
      }
      __syncthreads();
      {
        const int nl = t >> 1, mh = (t & 1) * 32;
        const int ng = n0 + nl, hh = ng >> 6, hd = ng & 63;
        const int bb = m0 >> 11;
        const int sb = (m0 & (S - 1)) + ph * 64 + mh;
        short* vdst = dst + (((bb * H + hh) * HD + hd) * S) + sb;
#pragma unroll
        for (int k2 = 0; k2 < 4; ++k2)
          *(bf16x8*)&vdst[k2 * 8] = *(const bf16x8*)&Cs[nl * 72 + mh + k2 * 8];
      }
      __syncthreads();
    }
  } else {
#pragma unroll
    for (int i = 0; i < 4; ++i) {
#pragma unroll
      for (int j = 0; j < 4; ++j) {
        const int n = n0 + wc * 64 + j * 16 + c;
        const int h = n >> 6, hd = n & 63;
        const float bn = bias[n];
#pragma unroll
        for (int r = 0; r < 4; ++r) {
          const int m = m0 + wr * 64 + i * 16 + g * 4 + r;
          const int bb = m >> 11, s = m & (S - 1);
          dst[((bb * H + h) * S + s) * HD + hd] = f2b(acc[i][j][r] + bn);
        }
      }
    }
  }
}

// ---------------- output GEMM: Out = att @ Wo^T + bo (fp32 out) ----------------
__global__ __launch_bounds__(256) void out_gemm(
    const short* __restrict__ Am, const short* __restrict__ W,
    const float* __restrict__ bias, float* __restrict__ Out) {
  const int tm = blockIdx.x & 63;
  const int tn = blockIdx.x >> 6;
  const int m0 = tm * 128, n0 = tn * 128;
  const int t = threadIdx.x;
  const int lane = t & 63, w = t >> 6;
  const int g = lane >> 4, c = lane & 15;
  const int wr = w >> 1, wc = w & 1;

  __shared__ __align__(16) short As[128 * LP];
  __shared__ __align__(16) short Bs[128 * LP];

  f32x4 acc[4][4];
  const f32x4 fz = {0.f, 0.f, 0.f, 0.f};
#pragma unroll
  for (int i = 0; i < 4; ++i)
#pragma unroll
    for (int j = 0; j < 4; ++j) acc[i][j] = fz;

  const int r0 = t >> 2, c0 = (t & 3) * 8;
  const int r1 = r0 + 64;

  for (int kt = 0; kt < DMODEL / 32; ++kt) {
    const int k0 = kt * 32;
    bf16x8 a0 = *(const bf16x8*)&Am[(m0 + r0) * DMODEL + k0 + c0];
    bf16x8 a1 = *(const bf16x8*)&Am[(m0 + r1) * DMODEL + k0 + c0];
    bf16x8 b0 = *(const bf16x8*)&W[(n0 + r0) * DMODEL + k0 + c0];
    bf16x8 b1 = *(const bf16x8*)&W[(n0 + r1) * DMODEL + k0 + c0];
    __syncthreads();
    *(bf16x8*)&As[r0 * LP + c0] = a0;
    *(bf16x8*)&As[r1 * LP + c0] = a1;
    *(bf16x8*)&Bs[r0 * LP + c0] = b0;
    *(bf16x8*)&Bs[r1 * LP + c0] = b1;
    __syncthreads();
    bf16x8 af[4], bfr[4];
#pragma unroll
    for (int i = 0; i < 4; ++i)
      af[i] = *(const bf16x8*)&As[(wr * 64 + i * 16 + c) * LP + g * 8];
#pragma unroll
    for (int j = 0; j < 4; ++j)
      bfr[j] = *(const bf16x8*)&Bs[(wc * 64 + j * 16 + c) * LP + g * 8];
#pragma unroll
    for (int i = 0; i < 4; ++i)
#pragma unroll
      for (int j = 0; j < 4; ++j)
        acc[i][j] = MFMA16(af[i], bfr[j], acc[i][j]);
  }

#pragma unroll
  for (int i = 0; i < 4; ++i) {
#pragma unroll
    for (int j = 0; j < 4; ++j) {
      const int n = n0 + wc * 64 + j * 16 + c;
      const float bn = bias[n];
#pragma unroll
      for (int r = 0; r < 4; ++r) {
        const int m = m0 + wr * 64 + i * 16 + g * 4 + r;
        Out[m * DMODEL + n] = acc[i][j][r] + bn;
      }
    }
  }
}

// ---------------- flash attention: swapped-QK^T 32x32, LDS-staged K/V via gload_lds ----------------
// 4 waves x 32 q-rows. K tile [64 kv][64 hd], V^T tile [64 d][64 kv] staged once per
// block (inverse-swizzled source, swizzled b128 reads). Row-sum via MFMA-ones (lst = osum[0]).
__global__ __launch_bounds__(256, 2) void attn_kernel(
    const short* __restrict__ Qp, const short* __restrict__ Kp,
    const short* __restrict__ VTp, short* __restrict__ att) {
  const int bid = blockIdx.x;
  const int swzb = (bid & 7) * 64 + (bid >> 3);  // 512 % 8 == 0: bijective
  const int qt = swzb & 15;
  const int bh = swzb >> 4;
  const int b = bh >> 3, h = bh & 7;
  const short* Q  = Qp  + bh * (S * HD);
  const char*  Kg = (const char*)(Kp  + bh * (S * HD));
  const char*  Vg = (const char*)(VTp + bh * (HD * S));

  const int t = threadIdx.x;
  const int lane = t & 63, w = t >> 6;
  const int l31 = lane & 31, hi = lane >> 5;
  const int q0 = qt * 128 + w * 32;

  __shared__ __align__(16) char smem[2 * 16384];  // [buf][K 8KB | V^T 8KB]

  // per-lane staging source offsets (inverse-swizzled: linear LDS + swizzled read)
  const int rowi = lane >> 3;
  const int swzs = ((lane & 7) * 16) ^ (rowi << 4);
  const char* ksrc0 = Kg + (w * 16 + rowi) * 128 + swzs;   // + kt*8192
  const char* ksrc1 = ksrc0 + 8 * 128;
  const char* vsrc0 = Vg + (w * 16 + rowi) * 4096 + swzs;  // + kt*128
  const char* vsrc1 = vsrc0 + 8 * 4096;

  // Q B-frags (col = q = lane&31, k = hd = ks*16 + hi*8 + j)
  bf16x8 qf[4];
#pragma unroll
  for (int ks = 0; ks < 4; ++ks)
    qf[ks] = *(const bf16x8*)&Q[(q0 + l31) * HD + ks * 16 + hi * 8];

  bf16x8 ones;
#pragma unroll
  for (int i = 0; i < 8; ++i) ones[i] = (short)0x3F80;  // bf16 1.0

  f32x16 o0, o1, osum;  // o^T accumulators + MFMA row-sum (lst = osum[0])
#pragma unroll
  for (int i = 0; i < 16; ++i) { o0[i] = 0.f; o1[i] = 0.f; osum[i] = 0.f; }
  float mst = -1e30f;

  // prologue: stage tile 0 into buf 0
  glds16(ksrc0, smem + w * 2048);
  glds16(ksrc1, smem + w * 2048 + 1024);
  glds16(vsrc0, smem + 8192 + w * 2048);
  glds16(vsrc1, smem + 8192 + w * 2048 + 1024);
  __syncthreads();

  const float SCL = 0.18033688011112042f;  // log2(e)/sqrt(HD)
  const int fswz = (l31 & 7) << 4;         // frag-read swizzle

  for (int kt = 0; kt < 32; ++kt) {
    const int cb = (kt & 1) * 16384;

    // issue staging of tile kt+1 into the other buffer (drains at __syncthreads)
    if (kt < 31) {
      char* nb = smem + (cb ^ 16384);
      const size_t ko = (size_t)(kt + 1) * 8192;
      const size_t vo = (size_t)(kt + 1) * 128;
      glds16(ksrc0 + ko, nb + w * 2048);
      glds16(ksrc1 + ko, nb + w * 2048 + 1024);
      glds16(vsrc0 + vo, nb + 8192 + w * 2048);
      glds16(vsrc1 + vo, nb + 8192 + w * 2048 + 1024);
    }

    // QK^T swapped: S^T[kv][q]; K A-frags from LDS (swizzled read)
    f32x16 sa0, sa1;
#pragma unroll
    for (int i = 0; i < 16; ++i) { sa0[i] = 0.f; sa1[i] = 0.f; }
    __builtin_amdgcn_s_setprio(1);
#pragma unroll
    for (int ks = 0; ks < 4; ++ks) {
      const int col = (ks * 32 + hi * 16) ^ fswz;
      const bf16x8 k0 = *(const bf16x8*)&smem[cb + l31 * 128 + col];
      const bf16x8 k1 = *(const bf16x8*)&smem[cb + (32 + l31) * 128 + col];
      sa0 = MFMA32(k0, qf[ks], sa0);
      sa1 = MFMA32(k1, qf[ks], sa1);
    }
    __builtin_amdgcn_s_setprio(0);

    // ---- in-register online softmax (per-lane q, kv split across hi) ----
    float u0 = fmax3(fmax3(sa0[0], sa0[1], sa0[2]), fmax3(sa0[3], sa0[4], sa0[5]),
                     fmax3(sa0[6], sa0[7], sa0[8]));
    float u1 = fmax3(fmax3(sa0[9], sa0[10], sa0[11]), fmax3(sa0[12], sa0[13], sa0[14]),
                     sa0[15]);
    float u2 = fmax3(fmax3(sa1[0], sa1[1], sa1[2]), fmax3(sa1[3], sa1[4], sa1[5]),
                     fmax3(sa1[6], sa1[7], sa1[8]));
    float u3 = fmax3(fmax3(sa1[9], sa1[10], sa1[11]), fmax3(sa1[12], sa1[13], sa1[14]),
                     sa1[15]);
    float mloc = fmax3(fmaxf(u0, u1), u2, u3);
    const float mx = fmaxf(mloc, __shfl_xor(mloc, 32, 64));
    const float mxs = mx * SCL;

    if (!__all(mxs - mst <= 8.0f)) {  // defer-max (T13)
      const float mn = fmaxf(mst, mxs);
      const float corr = exp2f(mst - mn);
      osum[0] *= corr;
#pragma unroll
      for (int i = 0; i < 16; ++i) { o0[i] *= corr; o1[i] *= corr; }
      mst = mn;
    }

#pragma unroll
    for (int i = 0; i < 16; ++i) {
      sa0[i] = exp2f(__builtin_fmaf(sa0[i], SCL, -mst));
      sa1[i] = exp2f(__builtin_fmaf(sa1[i], SCL, -mst));
    }

    // ---- P -> bf16 words; permlane32_swap assembles PV B-frags (T12, verified R3) ----
    unsigned int wrd0[8], wrd1[8];
#pragma unroll
    for (int i = 0; i < 8; ++i) {
      asm("v_cvt_pk_bf16_f32 %0, %1, %2" : "=v"(wrd0[i]) : "v"(sa0[2 * i]), "v"(sa0[2 * i + 1]));
      asm("v_cvt_pk_bf16_f32 %0, %1, %2" : "=v"(wrd1[i]) : "v"(sa1[2 * i]), "v"(sa1[2 * i + 1]));
    }

    // PV: o^T += V^T @ P; row-sum: osum += ones @ P (denominator on the MFMA pipe)
    __builtin_amdgcn_s_setprio(1);
#pragma unroll
    for (int ks = 0; ks < 4; ++ks) {
      const int i0 = (ks & 1) * 4;
      unsigned int a0 = (ks < 2) ? wrd0[i0 + 0] : wrd1[i0 + 0];
      unsigned int b0 = (ks < 2) ? wrd0[i0 + 2] : wrd1[i0 + 2];
      unsigned int a1 = (ks < 2) ? wrd0[i0 + 1] : wrd1[i0 + 1];
      unsigned int b1 = (ks < 2) ? wrd0[i0 + 3] : wrd1[i0 + 3];
      asm("v_permlane32_swap_b32 %0, %1" : "+v"(a0), "+v"(b0));
      asm("v_permlane32_swap_b32 %0, %1" : "+v"(a1), "+v"(b1));
      u32x4 fw;
      fw[0] = a0; fw[1] = a1; fw[2] = b0; fw[3] = b1;
      const bf16x8 pfrag = __builtin_bit_cast(bf16x8, fw);
      const int col = (ks * 32 + hi * 16) ^ fswz;
      const bf16x8 va0 = *(const bf16x8*)&smem[cb + 8192 + l31 * 128 + col];
      const bf16x8 va1 = *(const bf16x8*)&smem[cb + 8192 + (32 + l31) * 128 + col];
      o0 = MFMA32(va0, pfrag, o0);
      o1 = MFMA32(va1, pfrag, o1);
      osum = MFMA32(ones, pfrag, osum);
    }
    __builtin_amdgcn_s_setprio(0);

    // staging landed + all frag reads done
    __syncthreads();
  }

  // epilogue: att[b*S + q][h*HD + d] = o^T / osum[0]
  const float inv = 1.0f / osum[0];
  short* arow = att + (b * S + q0 + l31) * DMODEL + h * HD;
#pragma unroll
  for (int dt = 0; dt < 2; ++dt) {
#pragma unroll
    for (int rr = 0; rr < 4; ++rr) {
      float v0 = (dt ? o1[4 * rr + 0] : o0[4 * rr + 0]) * inv;
      float v1 = (dt ? o1[4 * rr + 1] : o0[4 * rr + 1]) * inv;
      float v2 = (dt ? o1[4 * rr + 2] : o0[4 * rr + 2]) * inv;
      float v3 = (dt ? o1[4 * rr + 3] : o0[4 * rr + 3]) * inv;
      unsigned int w0, w1;
      asm("v_cvt_pk_bf16_f32 %0, %1, %2" : "=v"(w0) : "v"(v0), "v"(v1));
      asm("v_cvt_pk_bf16_f32 %0, %1, %2" : "=v"(w1) : "v"(v2), "v"(v3));
      uint2 pk2;
      pk2.x = w0; pk2.y = w1;
      *(uint2*)&arow[dt * 32 + rr * 8 + hi * 4] = pk2;
    }
  }
}

extern "C" void kernel_launch(void* const* d_in, const int* in_sizes, int n_in,
                              void* d_out, int out_size, void* d_ws, size_t ws_size,
                              hipStream_t stream) {
  const float* query = (const float*)d_in[0];
  const float* key_  = (const float*)d_in[1];
  const float* value = (const float*)d_in[2];
  const float* Wq = (const float*)d_in[3];
  const float* bq = (const float*)d_in[4];
  const float* Wk = (const float*)d_in[5];
  const float* bk = (const float*)d_in[6];
  const float* Wv = (const float*)d_in[7];
  const float* bv = (const float*)d_in[8];
  const float* Wo = (const float*)d_in[9];
  const float* bo = (const float*)d_in[10];
  float* out = (float*)d_out;

  char* ws = (char*)d_ws;
  const size_t WB_BYTES  = (size_t)4 * DMODEL * DMODEL * 2;  // 2 MiB
  const size_t MAT_BYTES = (size_t)M * DMODEL * 2;           // 8 MiB each
  short* Wb  = (short*)ws;
  short* Qp  = (short*)(ws + WB_BYTES);
  short* Kp  = (short*)(ws + WB_BYTES + MAT_BYTES);
  short* Vp  = (short*)(ws + WB_BYTES + 2 * MAT_BYTES);   // transposed [B,H,HD,S]
  short* att = (short*)(ws + WB_BYTES + 3 * MAT_BYTES);

  convert_w<<<dim3(128, 4), 256, 0, stream>>>(Wq, Wk, Wv, Wo, Wb);
  proj_gemm<<<dim3(256, 3), 256, 0, stream>>>(query, key_, value, Wb, bq, bk, bv, Qp, Kp, Vp);
  attn_kernel<<<dim3(512), 256, 0, stream>>>(Qp, Kp, Vp, att);
  out_gemm<<<dim3(256), 256, 0, stream>>>(att, Wb + 3 * DMODEL * DMODEL, bo, out);
}